// Round 2
// baseline (2556.398 us; speedup 1.0000x reference)
//
#include <hip/hip_runtime.h>

#define IMG 224
#define PATCHSZ 16
#define CHN 3
#define DDIM 768
#define ROWN 14
#define NPATCH 196
#define PDIM 768
#define BATCH 32

#define DTILE 256
#define KCHUNK 64
#define NCHUNK (PDIM / KCHUNK)   // 12
#define WGROUP 8
#define NGROUP (KCHUNK / WGROUP) // 8

// Fused: per patch n: out[:,n,:] = patches(x)[n] (32x768) * W[n] (768x768) + b[n]
// grid = 196*3, block 256. Per thread: 8 batches x 4 d-cols.
// W stream: register double-buffer, 8 float4 in flight (the MLP fix).
// P staging: read directly from x (8 consecutive k = contiguous row segment),
// LDS ping-pong, loads issued one full chunk early.
__global__ __launch_bounds__(256, 2) void patch_gemm_kernel(
    const float* __restrict__ x,    // [32][3][224][224]
    const float* __restrict__ W,    // [196][768][768]
    const float* __restrict__ bias, // [196][768]
    float* __restrict__ out)        // [32][196][768]
{
    __shared__ float ap[2][KCHUNK][BATCH];  // 16 KB ping-pong, [k][b]

    const int blk  = blockIdx.x;
    const int n    = blk / 3;
    const int dblk = blk % 3;
    const int tid  = threadIdx.x;
    const int dg   = tid & 63;      // 64 d-lanes per wave -> 1KB coalesced W rows
    const int bg   = tid >> 6;      // wave-uniform batch group 0..3
    const int b0   = bg * 8;
    const int d    = dblk * DTILE + dg * 4;

    const float* Wn = W + (size_t)n * PDIM * DDIM + d;

    // staging mapping: thread -> (batch sb, 8 consecutive k at sk)
    const int sb = tid >> 3;          // 0..31
    const int sk = (tid & 7) * 8;     // 0,8,...,56
    const int rr = n / ROWN, cc = n % ROWN;

    // x address for chunk c: k0 = c*64 + sk; ch=k0>>8, py=(k0>>4)&15, px=k0&15
    // 8 consecutive k stay within one image row (px in {0,8}).
    auto xsrc = [&](int c) {
        int k0 = c * KCHUNK + sk;
        int ch = k0 >> 8;
        int py = (k0 >> 4) & 15;
        int px = k0 & 15;
        return x + (((size_t)sb * CHN + ch) * IMG + (rr * PATCHSZ + py)) * IMG
                 + cc * PATCHSZ + px;
    };

    float acc[8][4];
#pragma unroll
    for (int i = 0; i < 8; ++i)
#pragma unroll
        for (int j = 0; j < 4; ++j) acc[i][j] = 0.f;

    // stage chunk 0
    {
        const float* xs = xsrc(0);
        float4 v0 = *reinterpret_cast<const float4*>(xs);
        float4 v1 = *reinterpret_cast<const float4*>(xs + 4);
        float (*apb)[BATCH] = ap[0];
        apb[sk + 0][sb] = v0.x; apb[sk + 1][sb] = v0.y;
        apb[sk + 2][sb] = v0.z; apb[sk + 3][sb] = v0.w;
        apb[sk + 4][sb] = v1.x; apb[sk + 5][sb] = v1.y;
        apb[sk + 6][sb] = v1.z; apb[sk + 7][sb] = v1.w;
    }
    // issue P loads for chunk 1 (consumed at end of chunk 0's compute)
    const float* xs1 = xsrc(1);
    float4 pv0 = *reinterpret_cast<const float4*>(xs1);
    float4 pv1 = *reinterpret_cast<const float4*>(xs1 + 4);
    __syncthreads();

    // W pipeline prologue: group 0 into wbuf[0]
    float4 wbuf[2][WGROUP];
#pragma unroll
    for (int j = 0; j < WGROUP; ++j)
        wbuf[0][j] = *reinterpret_cast<const float4*>(Wn + (size_t)j * DDIM);

#pragma unroll 1
    for (int c = 0; c < NCHUNK; ++c) {
        const float (*apc)[BATCH] = ap[c & 1];
#pragma unroll
        for (int g = 0; g < NGROUP; ++g) {
            // prefetch next 8-k group (crosses chunk boundary at g=7)
            const int knext = c * KCHUNK + (g + 1) * WGROUP;
            if (knext < PDIM) {
#pragma unroll
                for (int j = 0; j < WGROUP; ++j)
                    wbuf[(g + 1) & 1][j] = *reinterpret_cast<const float4*>(
                        Wn + (size_t)(knext + j) * DDIM);
            }
            // compute current group from wbuf[g&1]
#pragma unroll
            for (int jj = 0; jj < WGROUP; ++jj) {
                const int kk = g * WGROUP + jj;
                float4 w = wbuf[g & 1][jj];
                // wave-uniform broadcast LDS reads (conflict-free)
                float4 p01 = *reinterpret_cast<const float4*>(&apc[kk][b0]);
                float4 p23 = *reinterpret_cast<const float4*>(&apc[kk][b0 + 4]);
                float pv[8] = {p01.x, p01.y, p01.z, p01.w,
                               p23.x, p23.y, p23.z, p23.w};
#pragma unroll
                for (int i = 0; i < 8; ++i) {
                    acc[i][0] = fmaf(pv[i], w.x, acc[i][0]);
                    acc[i][1] = fmaf(pv[i], w.y, acc[i][1]);
                    acc[i][2] = fmaf(pv[i], w.z, acc[i][2]);
                    acc[i][3] = fmaf(pv[i], w.w, acc[i][3]);
                }
            }
        }
        if (c + 1 < NCHUNK) {
            // write next chunk (other buffer); single barrier per chunk:
            // previous readers of this buffer were fenced by last iteration's
            // barrier, and this barrier publishes the write.
            float (*apb)[BATCH] = ap[(c + 1) & 1];
            apb[sk + 0][sb] = pv0.x; apb[sk + 1][sb] = pv0.y;
            apb[sk + 2][sb] = pv0.z; apb[sk + 3][sb] = pv0.w;
            apb[sk + 4][sb] = pv1.x; apb[sk + 5][sb] = pv1.y;
            apb[sk + 6][sb] = pv1.z; apb[sk + 7][sb] = pv1.w;
            if (c + 2 < NCHUNK) {
                const float* xs = xsrc(c + 2);
                pv0 = *reinterpret_cast<const float4*>(xs);
                pv1 = *reinterpret_cast<const float4*>(xs + 4);
            }
            __syncthreads();
        }
    }

    float4 bv = *reinterpret_cast<const float4*>(bias + (size_t)n * DDIM + d);
#pragma unroll
    for (int i = 0; i < 8; ++i) {
        const int b = b0 + i;
        float4 o;
        o.x = acc[i][0] + bv.x;
        o.y = acc[i][1] + bv.y;
        o.z = acc[i][2] + bv.z;
        o.w = acc[i][3] + bv.w;
        *reinterpret_cast<float4*>(out + ((size_t)b * NPATCH + n) * DDIM + d) = o;
    }
}

extern "C" void kernel_launch(void* const* d_in, const int* in_sizes, int n_in,
                              void* d_out, int out_size, void* d_ws, size_t ws_size,
                              hipStream_t stream) {
    const float* x    = (const float*)d_in[0];
    const float* W    = (const float*)d_in[1];
    const float* bias = (const float*)d_in[2];
    float* out = (float*)d_out;

    patch_gemm_kernel<<<NPATCH * 3, 256, 0, stream>>>(x, W, bias, out);
}

// Round 3
// 2278.970 us; speedup vs baseline: 1.1217x; 1.1217x over previous
//
#include <hip/hip_runtime.h>

#define IMG 224
#define PATCHSZ 16
#define CHN 3
#define DDIM 768
#define ROWN 14
#define NPATCH 196
#define PDIM 768
#define BATCH 32

#define DTILE 256
#define KCHUNK 64
#define NCHUNK (PDIM / KCHUNK)   // 12
#define WGROUP 8
#define NGROUP (KCHUNK / WGROUP) // 8

// Kernel 1: x[32][3][224][224] -> P[196][32][768]
__global__ void extract_patches_kernel(const float* __restrict__ x,
                                       float* __restrict__ P) {
    int i = blockIdx.x * blockDim.x + threadIdx.x;
    if (i >= NPATCH * BATCH * PDIM) return;
    int k  = i % PDIM;
    int nb = i / PDIM;
    int b  = nb % BATCH;
    int n  = nb / BATCH;
    int ch = k >> 8;
    int py = (k >> 4) & 15;
    int px = k & 15;
    int r = n / ROWN, c = n % ROWN;
    P[i] = x[(((size_t)b * CHN + ch) * IMG + r * PATCHSZ + py) * IMG
             + c * PATCHSZ + px];
}

// one k-slice: broadcast P row kk from LDS, 32 FMAs into acc
#define ACC_ROW(i, pv, wj)                                                   \
    acc[i][0] = fmaf(pv, wj.x, acc[i][0]);                                   \
    acc[i][1] = fmaf(pv, wj.y, acc[i][1]);                                   \
    acc[i][2] = fmaf(pv, wj.z, acc[i][2]);                                   \
    acc[i][3] = fmaf(pv, wj.w, acc[i][3]);

#define CKJ(j, wj) do {                                                      \
    const float* pp = apcf + (size_t)(kb + j) * BATCH + b0;                  \
    float4 p01 = *reinterpret_cast<const float4*>(pp);                       \
    float4 p23 = *reinterpret_cast<const float4*>(pp + 4);                   \
    ACC_ROW(0, p01.x, wj) ACC_ROW(1, p01.y, wj)                              \
    ACC_ROW(2, p01.z, wj) ACC_ROW(3, p01.w, wj)                              \
    ACC_ROW(4, p23.x, wj) ACC_ROW(5, p23.y, wj)                              \
    ACC_ROW(6, p23.z, wj) ACC_ROW(7, p23.w, wj)                              \
} while (0)

// per patch n: out[:,n,:] = P[n] (32x768) * W[n] (768x768) + bias[n]
// grid 196*3, block 256; thread tile 8 batches x 4 d-cols.
__global__ __launch_bounds__(256, 2) void patch_gemm_kernel(
    const float* __restrict__ P,    // [196][32][768]
    const float* __restrict__ W,    // [196][768][768]
    const float* __restrict__ bias, // [196][768]
    float* __restrict__ out)        // [32][196][768]
{
    __shared__ float ap[2][KCHUNK][BATCH];  // 16 KB ping-pong, [k][b]

    const int blk  = blockIdx.x;
    const int n    = blk / 3;
    const int dblk = blk % 3;
    const int tid  = threadIdx.x;
    const int dg   = tid & 63;      // 64 d-lanes/wave -> 1KB coalesced W rows
    const int bg   = tid >> 6;      // wave-uniform batch group 0..3
    const int b0   = bg * 8;
    const int d    = dblk * DTILE + dg * 4;

    const float* Wn = W + (size_t)n * PDIM * DDIM + d;
    const float* Pn = P + (size_t)n * BATCH * PDIM;

    // staging mapping: thread -> (batch sb, 8 consecutive k at sk)
    const int sb = tid >> 3;          // 0..31
    const int sk = (tid & 7) * 8;     // 0,8,...,56

    float acc[8][4];
#pragma unroll
    for (int i = 0; i < 8; ++i)
#pragma unroll
        for (int j = 0; j < 4; ++j) acc[i][j] = 0.f;

    // stage chunk 0
    {
        const float* s = Pn + (size_t)sb * PDIM + sk;
        float4 v0 = *reinterpret_cast<const float4*>(s);
        float4 v1 = *reinterpret_cast<const float4*>(s + 4);
        float (*apb)[BATCH] = ap[0];
        apb[sk + 0][sb] = v0.x; apb[sk + 1][sb] = v0.y;
        apb[sk + 2][sb] = v0.z; apb[sk + 3][sb] = v0.w;
        apb[sk + 4][sb] = v1.x; apb[sk + 5][sb] = v1.y;
        apb[sk + 6][sb] = v1.z; apb[sk + 7][sb] = v1.w;
    }
    // register-prefetch chunk 1's P
    float4 pn0, pn1;
    {
        const float* s = Pn + (size_t)sb * PDIM + KCHUNK + sk;
        pn0 = *reinterpret_cast<const float4*>(s);
        pn1 = *reinterpret_cast<const float4*>(s + 4);
    }
    __syncthreads();

#pragma unroll 1
    for (int c = 0; c < NCHUNK; ++c) {
        const float* apcf = (const float*)ap[c & 1];
        const float* Wc = Wn + (size_t)(c * KCHUNK) * DDIM;
#pragma unroll
        for (int g = 0; g < NGROUP; ++g) {
            const float* Wp = Wc + (size_t)(g * WGROUP) * DDIM;
            const int kb = g * WGROUP;
            // 8 independent wave-coalesced loads, all issued before use
            float4 w0 = *reinterpret_cast<const float4*>(Wp + 0 * (size_t)DDIM);
            float4 w1 = *reinterpret_cast<const float4*>(Wp + 1 * (size_t)DDIM);
            float4 w2 = *reinterpret_cast<const float4*>(Wp + 2 * (size_t)DDIM);
            float4 w3 = *reinterpret_cast<const float4*>(Wp + 3 * (size_t)DDIM);
            float4 w4 = *reinterpret_cast<const float4*>(Wp + 4 * (size_t)DDIM);
            float4 w5 = *reinterpret_cast<const float4*>(Wp + 5 * (size_t)DDIM);
            float4 w6 = *reinterpret_cast<const float4*>(Wp + 6 * (size_t)DDIM);
            float4 w7 = *reinterpret_cast<const float4*>(Wp + 7 * (size_t)DDIM);
            CKJ(0, w0); CKJ(1, w1); CKJ(2, w2); CKJ(3, w3);
            CKJ(4, w4); CKJ(5, w5); CKJ(6, w6); CKJ(7, w7);
        }
        if (c + 1 < NCHUNK) {
            float (*apb)[BATCH] = ap[(c + 1) & 1];
            apb[sk + 0][sb] = pn0.x; apb[sk + 1][sb] = pn0.y;
            apb[sk + 2][sb] = pn0.z; apb[sk + 3][sb] = pn0.w;
            apb[sk + 4][sb] = pn1.x; apb[sk + 5][sb] = pn1.y;
            apb[sk + 6][sb] = pn1.z; apb[sk + 7][sb] = pn1.w;
            if (c + 2 < NCHUNK) {
                const float* s = Pn + (size_t)sb * PDIM + (c + 2) * KCHUNK + sk;
                pn0 = *reinterpret_cast<const float4*>(s);
                pn1 = *reinterpret_cast<const float4*>(s + 4);
            }
            __syncthreads();
        }
    }

    float4 bv = *reinterpret_cast<const float4*>(bias + (size_t)n * DDIM + d);
#pragma unroll
    for (int i = 0; i < 8; ++i) {
        const int b = b0 + i;
        float4 o;
        o.x = acc[i][0] + bv.x;
        o.y = acc[i][1] + bv.y;
        o.z = acc[i][2] + bv.z;
        o.w = acc[i][3] + bv.w;
        *reinterpret_cast<float4*>(out + ((size_t)b * NPATCH + n) * DDIM + d) = o;
    }
}

extern "C" void kernel_launch(void* const* d_in, const int* in_sizes, int n_in,
                              void* d_out, int out_size, void* d_ws, size_t ws_size,
                              hipStream_t stream) {
    const float* x    = (const float*)d_in[0];
    const float* W    = (const float*)d_in[1];
    const float* bias = (const float*)d_in[2];
    float* out = (float*)d_out;
    float* P   = (float*)d_ws;   // 196*32*768*4 = 19.3 MB

    int total = NPATCH * BATCH * PDIM;
    extract_patches_kernel<<<(total + 255) / 256, 256, 0, stream>>>(x, P);
    patch_gemm_kernel<<<NPATCH * 3, 256, 0, stream>>>(P, W, bias, out);
}

// Round 4
// 164.290 us; speedup vs baseline: 15.5603x; 13.8716x over previous
//
#include <hip/hip_runtime.h>

#define IMG 224
#define PATCHSZ 16
#define CHN 3
#define DDIM 768
#define ROWN 14
#define NPATCH 196
#define PDIM 768
#define BATCH 32

#define DTILE 256
#define KCHUNK 64                 // P chunk rows
#define NCHUNK (PDIM / KCHUNK)    // 12
#define KSUB 16                   // W subchunk rows
#define NSUB (PDIM / KSUB)        // 48

// Kernel 1: x[32][3][224][224] -> P[196][32][768]
__global__ void extract_patches_kernel(const float* __restrict__ x,
                                       float* __restrict__ P) {
    int i = blockIdx.x * blockDim.x + threadIdx.x;
    if (i >= NPATCH * BATCH * PDIM) return;
    int k  = i % PDIM;
    int nb = i / PDIM;
    int b  = nb % BATCH;
    int n  = nb / BATCH;
    int ch = k >> 8;
    int py = (k >> 4) & 15;
    int px = k & 15;
    int r = n / ROWN, c = n % ROWN;
    P[i] = x[(((size_t)b * CHN + ch) * IMG + r * PATCHSZ + py) * IMG
             + c * PATCHSZ + px];
}

#define ACC_ROW(i, pv, wj)                                                   \
    acc[i][0] = fmaf(pv, wj.x, acc[i][0]);                                   \
    acc[i][1] = fmaf(pv, wj.y, acc[i][1]);                                   \
    acc[i][2] = fmaf(pv, wj.z, acc[i][2]);                                   \
    acc[i][3] = fmaf(pv, wj.w, acc[i][3]);

// per patch n: out[:,n,:] = P[n] (32x768) * W[n] (768x768) + bias[n]
// grid 196*3, block 256; thread tile 8 batches x 4 d-cols.
// W: global_load_lds double-buffer (no VGPR round trip -> no spill).
__global__ __launch_bounds__(256, 2) void patch_gemm_kernel(
    const float* __restrict__ P,    // [196][32][768]
    const float* __restrict__ W,    // [196][768][768]
    const float* __restrict__ bias, // [196][768]
    float* __restrict__ out)        // [32][196][768]
{
    __shared__ __align__(16) float wt[2][KSUB][DTILE];   // 32 KB W ping-pong
    __shared__ __align__(16) float ap[2][KCHUNK][BATCH]; // 16 KB P ping-pong

    const int blk  = blockIdx.x;
    const int n    = blk / 3;
    const int dblk = blk % 3;
    const int tid  = threadIdx.x;
    const int ln   = tid & 63;      // lane; also d-quad index
    const int wv   = tid >> 6;      // wave 0..3
    const int b0   = wv * 8;        // batch group per wave
    const int d    = dblk * DTILE + ln * 4;

    const float* Wn0 = W + (size_t)n * PDIM * DDIM + dblk * DTILE; // row base
    const float* Pn  = P + (size_t)n * BATCH * PDIM;

    // P staging mapping: thread -> (batch sb, 8 consecutive k at sk)
    const int sb = tid >> 3;          // 0..31
    const int sk = (tid & 7) * 8;     // 0..56

    float acc[8][4];
#pragma unroll
    for (int i = 0; i < 8; ++i)
#pragma unroll
        for (int j = 0; j < 4; ++j) acc[i][j] = 0.f;

    // issue one W subchunk (16 rows x 256 cols) into wt[u&1].
    // per wave: 4 x global_load_lds_dwordx4, each stages one 1KB row.
    auto issueW = [&](int u) {
        const float* src = Wn0 + (size_t)u * KSUB * DDIM;
        float* dst = &wt[u & 1][0][0];
#pragma unroll
        for (int j = 0; j < 4; ++j) {
            const int row = wv * 4 + j;
            __builtin_amdgcn_global_load_lds(
                (const __attribute__((address_space(1))) unsigned int*)
                    (src + (size_t)row * DDIM + ln * 4),
                (__attribute__((address_space(3))) unsigned int*)
                    (dst + row * DTILE + ln * 4),
                16, 0, 0);
        }
    };

    // prologue: stage P chunk 0, prefetch P chunk 1, issue W subchunk 0
    {
        const float* s = Pn + (size_t)sb * PDIM + sk;
        float4 v0 = *reinterpret_cast<const float4*>(s);
        float4 v1 = *reinterpret_cast<const float4*>(s + 4);
        float (*apb)[BATCH] = ap[0];
        apb[sk + 0][sb] = v0.x; apb[sk + 1][sb] = v0.y;
        apb[sk + 2][sb] = v0.z; apb[sk + 3][sb] = v0.w;
        apb[sk + 4][sb] = v1.x; apb[sk + 5][sb] = v1.y;
        apb[sk + 6][sb] = v1.z; apb[sk + 7][sb] = v1.w;
    }
    float4 pn0, pn1;
    {
        const float* s = Pn + (size_t)sb * PDIM + KCHUNK + sk;
        pn0 = *reinterpret_cast<const float4*>(s);
        pn1 = *reinterpret_cast<const float4*>(s + 4);
    }
    issueW(0);

#pragma unroll 1
    for (int u = 0; u < NSUB; ++u) {
        __syncthreads();   // drains vmcnt+lgkmcnt: W(u) landed, P writes visible
        if (u + 1 < NSUB) issueW(u + 1);

        const int c  = u >> 2;          // P chunk
        const int kb = (u & 3) * KSUB;  // k offset within P chunk
        const float* wbuf = &wt[u & 1][0][0] + ln * 4;
        const float* pbuf = &ap[c & 1][0][0] + b0;

#pragma unroll 4
        for (int kk = 0; kk < KSUB; ++kk) {
            float4 w = *reinterpret_cast<const float4*>(wbuf + kk * DTILE);
            const float* pp = pbuf + (size_t)(kb + kk) * BATCH;
            float4 p01 = *reinterpret_cast<const float4*>(pp);
            float4 p23 = *reinterpret_cast<const float4*>(pp + 4);
            ACC_ROW(0, p01.x, w) ACC_ROW(1, p01.y, w)
            ACC_ROW(2, p01.z, w) ACC_ROW(3, p01.w, w)
            ACC_ROW(4, p23.x, w) ACC_ROW(5, p23.y, w)
            ACC_ROW(6, p23.z, w) ACC_ROW(7, p23.w, w)
        }

        // at the last subchunk of chunk c: stage P chunk c+1, prefetch c+2
        if ((u & 3) == 3 && c + 1 < NCHUNK) {
            float (*apb)[BATCH] = ap[(c + 1) & 1];
            apb[sk + 0][sb] = pn0.x; apb[sk + 1][sb] = pn0.y;
            apb[sk + 2][sb] = pn0.z; apb[sk + 3][sb] = pn0.w;
            apb[sk + 4][sb] = pn1.x; apb[sk + 5][sb] = pn1.y;
            apb[sk + 6][sb] = pn1.z; apb[sk + 7][sb] = pn1.w;
            if (c + 2 < NCHUNK) {
                const float* s = Pn + (size_t)sb * PDIM + (c + 2) * KCHUNK + sk;
                pn0 = *reinterpret_cast<const float4*>(s);
                pn1 = *reinterpret_cast<const float4*>(s + 4);
            }
        }
    }

    float4 bv = *reinterpret_cast<const float4*>(bias + (size_t)n * DDIM + d);
#pragma unroll
    for (int i = 0; i < 8; ++i) {
        const int b = b0 + i;
        float4 o;
        o.x = acc[i][0] + bv.x;
        o.y = acc[i][1] + bv.y;
        o.z = acc[i][2] + bv.z;
        o.w = acc[i][3] + bv.w;
        *reinterpret_cast<float4*>(out + ((size_t)b * NPATCH + n) * DDIM + d) = o;
    }
}

extern "C" void kernel_launch(void* const* d_in, const int* in_sizes, int n_in,
                              void* d_out, int out_size, void* d_ws, size_t ws_size,
                              hipStream_t stream) {
    const float* x    = (const float*)d_in[0];
    const float* W    = (const float*)d_in[1];
    const float* bias = (const float*)d_in[2];
    float* out = (float*)d_out;
    float* P   = (float*)d_ws;   // 196*32*768*4 = 19.3 MB

    int total = NPATCH * BATCH * PDIM;
    extract_patches_kernel<<<(total + 255) / 256, 256, 0, stream>>>(x, P);
    patch_gemm_kernel<<<NPATCH * 3, 256, 0, stream>>>(P, W, bias, out);
}